// Round 3
// baseline (745.488 us; speedup 1.0000x reference)
//
#include <hip/hip_runtime.h>
#include <hip/hip_fp16.h>

#define MKEY 256        // K (key size)
#define NMEM 100000     // memory rows
#define NPAD 100096     // 782 * 128
#define NQ   2048       // queries
#define BM 128
#define BN 128
#define NTILES 782      // NPAD / BN
#define MTILES 16       // NQ / BM
#define NTG 98          // ceil(NTILES/8)
#define GRID (8 * MTILES * NTG)   // 12544, 32 blocks early-exit
#define LDKB 272        // padded A row stride in bytes (17 x 16B chunks; chunk 16 pad)
#define ALIMB 34816     // byte offset of lo-limb region in A LDS (2176 slots * 16B)

typedef _Float16 f16x8 __attribute__((ext_vector_type(8)));
typedef float f32x4 __attribute__((ext_vector_type(4)));

__device__ inline unsigned ord_f32(float f) {
  unsigned b = __float_as_uint(f);
  return (b & 0x80000000u) ? ~b : (b | 0x80000000u);
}

__device__ inline void gll16(const void* g, void* l) {
  __builtin_amdgcn_global_load_lds(
      (const __attribute__((address_space(1))) unsigned*)g,
      (__attribute__((address_space(3))) unsigned*)l, 16, 0, 0);
}

// split query fp32 -> fp16 hi/lo limbs; also zero-init best[]
__global__ void conv_query(const float* __restrict__ q,
                           unsigned short* __restrict__ qh,
                           unsigned short* __restrict__ ql,
                           unsigned long long* __restrict__ best) {
  const int i = blockIdx.x * 256 + threadIdx.x;
  float x = q[i];
  __half hh = __float2half(x);
  qh[i] = __half_as_ushort(hh);
  ql[i] = __half_as_ushort(__float2half(x - __half2float(hh)));
  if (i < NQ) best[i] = 0ull;
}

// split keys fp32 -> interleaved fp16 hi/lo limbs (row stride 512 hw: hi[256] lo[256])
// + inv key norm; zero-fill pad rows
__global__ void conv_keys(const float* __restrict__ mem,
                          unsigned short* __restrict__ khl,
                          float* __restrict__ rkn) {
  const int t = threadIdx.x, lane = t & 63, w = t >> 6;
  const int row = blockIdx.x * 4 + w;
  if (row < NMEM) {
    const float4 v = *(const float4*)&mem[(long)row * 512 + lane * 4];
    float fs[4] = {v.x, v.y, v.z, v.w};
    unsigned short hb[4], lb[4];
    float ss = 0.f;
#pragma unroll
    for (int c = 0; c < 4; ++c) {
      float x = fs[c];
      ss += x * x;
      __half hh = __float2half(x);
      hb[c] = __half_as_ushort(hh);
      lb[c] = __half_as_ushort(__float2half(x - __half2float(hh)));
    }
    *(ushort4*)&khl[(long)row * 512 + lane * 4] = make_ushort4(hb[0], hb[1], hb[2], hb[3]);
    *(ushort4*)&khl[(long)row * 512 + 256 + lane * 4] = make_ushort4(lb[0], lb[1], lb[2], lb[3]);
#pragma unroll
    for (int off = 32; off >= 1; off >>= 1) ss += __shfl_xor(ss, off, 64);
    if (lane == 0) rkn[row] = 1.0f / sqrtf(fmaxf(ss, 1e-30f));
  } else {
    *(ushort4*)&khl[(long)row * 512 + lane * 4] = make_ushort4(0, 0, 0, 0);
    *(ushort4*)&khl[(long)row * 512 + 256 + lane * 4] = make_ushort4(0, 0, 0, 0);
    if (lane == 0) rkn[row] = 0.f;
  }
}

// fused fp32-via-fp16x2 GEMM + per-query argmax.
// A (queries) via LDS (padded, per K-half staging); B (keys) direct global->VGPR.
__global__ __launch_bounds__(256, 2) void gemm_argmax(
    const unsigned short* __restrict__ qh, const unsigned short* __restrict__ ql,
    const unsigned short* __restrict__ khl, const float* __restrict__ rkn,
    unsigned long long* __restrict__ best) {
  __shared__ unsigned short A2[2 * 128 * (LDKB / 2)];  // 69632 B, limb-major slots
  __shared__ unsigned long long cand[BM][2];

  // XCD-clustered decode: same-ntile blocks land on the same XCD (ids = mod 8)
  const int id = blockIdx.x;
  const int mtile = (id >> 3) & 15;
  const int ntile = (id & 7) + 8 * (id >> 7);
  if (ntile >= NTILES) return;

  const int t = threadIdx.x;
  const int w = t >> 6;
  const int lane = t & 63;
  const int wr = w >> 1, wc = w & 1;
  const int q16 = lane >> 4, l16 = lane & 15;

  // --- staging precompute: wave w stages slots [w*1088, w*1088+1088) ---
  // slot s = limb*2176 + r*17 + ch  (ch 16 = pad -> dummy src); LDS byte = s*16
  int soff[17];
#pragma unroll
  for (int c = 0; c < 17; ++c) {
    int ls = (w & 1) * 1088 + c * 64 + lane;  // slot within this limb region
    int r = ls / 17;
    int ch = ls - r * 17;
    if (ch == 16) ch = 0;                     // pad slot -> dummy load (L1 hit)
    soff[c] = r * 512 + ch * 16;              // byte offset in qh/ql row-major
  }
  const char* asrc = (const char*)((w < 2) ? qh : ql) + (size_t)mtile * BM * 512;
  char* adst = (char*)A2 + w * 1088 * 16;

  // --- B base pointers: row (ntile*128 + 64*wc + 16*j + l16), stride 1024 B ---
  const char* bp[4];
#pragma unroll
  for (int j = 0; j < 4; ++j)
    bp[j] = (const char*)khl +
            (size_t)(ntile * BN + 64 * wc + 16 * j + l16) * 1024 + q16 * 16;

  f32x4 acc[4][4];
#pragma unroll
  for (int i = 0; i < 4; i++)
#pragma unroll
    for (int j = 0; j < 4; j++) acc[i][j] = (f32x4){0.f, 0.f, 0.f, 0.f};

  for (int h = 0; h < 2; ++h) {
    __syncthreads();
#pragma unroll
    for (int c = 0; c < 17; ++c)
      gll16(asrc + h * 256 + soff[c], adst + c * 1024);
    __syncthreads();  // drain A staging only; B loads issue after
#pragma unroll
    for (int ks = 0; ks < 4; ++ks) {
      const int abyte = ks * 64 + q16 * 16;
      const int bbyte = h * 256 + ks * 64;
      f16x8 ah[4], al[4], bh[4], bl[4];
#pragma unroll
      for (int i = 0; i < 4; ++i) {
        const int rbase = (64 * wr + 16 * i + l16) * LDKB + abyte;
        ah[i] = *(const f16x8*)((const char*)A2 + rbase);
        al[i] = *(const f16x8*)((const char*)A2 + ALIMB + rbase);
      }
#pragma unroll
      for (int j = 0; j < 4; ++j) {
        bh[j] = *(const f16x8*)(bp[j] + bbyte);
        bl[j] = *(const f16x8*)(bp[j] + 512 + bbyte);
      }
#pragma unroll
      for (int i = 0; i < 4; ++i)
#pragma unroll
        for (int j = 0; j < 4; ++j) {
          acc[i][j] = __builtin_amdgcn_mfma_f32_16x16x32_f16(ah[i], bh[j], acc[i][j], 0, 0, 0);
          acc[i][j] = __builtin_amdgcn_mfma_f32_16x16x32_f16(ah[i], bl[j], acc[i][j], 0, 0, 0);
          acc[i][j] = __builtin_amdgcn_mfma_f32_16x16x32_f16(al[i], bh[j], acc[i][j], 0, 0, 0);
        }
    }
  }

  // Epilogue: sim = dot * (1/kn); argmax with packed (ordered_sim<<32)|~idx
  int ncol[4];
  float rk[4];
#pragma unroll
  for (int j = 0; j < 4; j++) {
    ncol[j] = ntile * BN + 64 * wc + 16 * j + l16;
    rk[j] = (ncol[j] < NMEM) ? rkn[ncol[j]] : 0.f;
  }
#pragma unroll
  for (int i = 0; i < 4; i++) {
#pragma unroll
    for (int r = 0; r < 4; r++) {
      unsigned long long bp2 = 0ull;
#pragma unroll
      for (int j = 0; j < 4; j++) {
        if (ncol[j] < NMEM) {
          float s = acc[i][j][r] * rk[j];
          unsigned long long p =
              ((unsigned long long)ord_f32(s) << 32) | (unsigned)(~(unsigned)ncol[j]);
          bp2 = (p > bp2) ? p : bp2;
        }
      }
#pragma unroll
      for (int off = 1; off < 16; off <<= 1) {
        unsigned long long o = __shfl_xor(bp2, off, 64);
        bp2 = (o > bp2) ? o : bp2;
      }
      if (l16 == 0) cand[64 * wr + 16 * i + 4 * q16 + r][wc] = bp2;
    }
  }
  __syncthreads();
  if (t < BM) {
    unsigned long long a = cand[t][0], b = cand[t][1];
    unsigned long long m = (a > b) ? a : b;
    atomicMax(&best[mtile * BM + t], m);
  }
}

__global__ void gather_vals(const unsigned long long* __restrict__ best,
                            const float* __restrict__ mem, float* __restrict__ out) {
  const int b = blockIdx.x, lane = threadIdx.x; // 64 threads
  const unsigned idx = ~(unsigned)(best[b] & 0xFFFFFFFFull);
  const float4 v = *(const float4*)&mem[(long)idx * 512 + 256 + lane * 4];
  *(float4*)&out[(long)b * 256 + lane * 4] = v;
}

extern "C" void kernel_launch(void* const* d_in, const int* in_sizes, int n_in,
                              void* d_out, int out_size, void* d_ws, size_t ws_size,
                              hipStream_t stream) {
  const float* query = (const float*)d_in[0];
  const float* memory = (const float*)d_in[1];
  float* out = (float*)d_out;

  char* p = (char*)d_ws;
  unsigned short* qh = (unsigned short*)p; p += (size_t)NQ * MKEY * 2;
  unsigned short* ql = (unsigned short*)p; p += (size_t)NQ * MKEY * 2;
  unsigned short* khl = (unsigned short*)p; p += (size_t)NPAD * 512 * 2;
  float* rkn = (float*)p; p += (size_t)NPAD * 4;
  unsigned long long* best = (unsigned long long*)p; p += (size_t)NQ * 8;

  hipLaunchKernelGGL(conv_query, dim3(NQ * MKEY / 256), dim3(256), 0, stream,
                     query, qh, ql, best);
  hipLaunchKernelGGL(conv_keys, dim3(NPAD / 4), dim3(256), 0, stream, memory, khl, rkn);
  hipLaunchKernelGGL(gemm_argmax, dim3(GRID), dim3(256), 0, stream,
                     qh, ql, khl, rkn, best);
  hipLaunchKernelGGL(gather_vals, dim3(NQ), dim3(64), 0, stream, best, memory, out);
}

// Round 4
// 531.191 us; speedup vs baseline: 1.4034x; 1.4034x over previous
//
#include <hip/hip_runtime.h>
#include <hip/hip_fp16.h>
#include <float.h>

#define MKEY 256        // K (key size)
#define NMEM 100000     // memory rows
#define NPAD 100096     // 782 * 128
#define NQ   2048       // queries
#define BM 128
#define BN 128
#define LDK 72          // padded LDS row stride in halfwords (144 B = 9 x 16B chunks)
#define NTILES 782      // NPAD / BN
#define MTILES 16       // NQ / BM
#define GRID (128 * 98) // XCD-clustered id space; ntile>=782 early-exits

typedef _Float16 f16x8 __attribute__((ext_vector_type(8)));
typedef float f32x4 __attribute__((ext_vector_type(4)));

__device__ inline void gll16(const void* g, void* l) {
  __builtin_amdgcn_global_load_lds(
      (const __attribute__((address_space(1))) unsigned*)g,
      (__attribute__((address_space(3))) unsigned*)l, 16, 0, 0);
}

// query fp32 -> fp16 (hi limb only)
__global__ void conv_query(const float* __restrict__ q,
                           unsigned short* __restrict__ qh) {
  const int i = blockIdx.x * 256 + threadIdx.x;
  qh[i] = __half_as_ushort(__float2half(q[i]));
}

// keys fp32 -> fp16 + inv key norm; zero-fill pad rows
__global__ void conv_keys(const float* __restrict__ mem,
                          unsigned short* __restrict__ kh,
                          float* __restrict__ rkn) {
  const int t = threadIdx.x, lane = t & 63, w = t >> 6;
  const int row = blockIdx.x * 4 + w;
  if (row < NMEM) {
    const float4 v = *(const float4*)&mem[(long)row * 512 + lane * 4];
    float fs[4] = {v.x, v.y, v.z, v.w};
    unsigned short hb[4];
    float ss = 0.f;
#pragma unroll
    for (int c = 0; c < 4; ++c) {
      ss += fs[c] * fs[c];
      hb[c] = __half_as_ushort(__float2half(fs[c]));
    }
    *(ushort4*)&kh[(long)row * 256 + lane * 4] = make_ushort4(hb[0], hb[1], hb[2], hb[3]);
#pragma unroll
    for (int off = 32; off >= 1; off >>= 1) ss += __shfl_xor(ss, off, 64);
    if (lane == 0) rkn[row] = 1.0f / sqrtf(fmaxf(ss, 1e-30f));
  } else {
    *(ushort4*)&kh[(long)row * 256 + lane * 4] = make_ushort4(0, 0, 0, 0);
    if (lane == 0) rkn[row] = 0.f;
  }
}

// Pass 1: fp16 screening GEMM; writes per-(query, ntile) max score (dot * 1/kn)
__global__ __launch_bounds__(256, 4) void gemm_screen(
    const unsigned short* __restrict__ qh, const unsigned short* __restrict__ kh,
    const float* __restrict__ rkn, float* __restrict__ bmax) {
  __shared__ unsigned short Ah[BM * LDK], Bh[BN * LDK];
  __shared__ float cand[BM][2];

  // XCD-clustered decode: same-ntile blocks land on the same XCD (ids = mod 8)
  const int id = blockIdx.x;
  const int mtile = (id >> 3) & 15;
  const int ntile = (id & 7) + 8 * (id >> 7);
  if (ntile >= NTILES) return;

  const int t = threadIdx.x;
  const int w = t >> 6;
  const int lane = t & 63;
  const int wr = w >> 1, wc = w & 1;
  const int q16 = lane >> 4, l16 = lane & 15;

  // staging: waves 0,1 -> Ah; waves 2,3 -> Bh; each wave 9 calls (576 slots)
  int soff[9];
#pragma unroll
  for (int c = 0; c < 9; ++c) {
    int s = (w & 1) * 576 + c * 64 + lane;  // slot 0..1151 within array
    int r = s / 9, ch = s - r * 9;
    if (ch == 8) ch = 0;                    // pad chunk -> dummy load (L1 hit)
    soff[c] = r * 512 + ch * 16;            // bytes in source (row stride 512B)
  }
  const char* asrc = (const char*)((w < 2) ? qh : kh) +
                     (size_t)(((w < 2) ? mtile : ntile) * 128) * 512;
  char* adst = (char*)((w < 2) ? Ah : Bh) + (w & 1) * 576 * 16;

  f32x4 acc[4][4];
#pragma unroll
  for (int i = 0; i < 4; i++)
#pragma unroll
    for (int j = 0; j < 4; j++) acc[i][j] = (f32x4){0.f, 0.f, 0.f, 0.f};

  for (int k0 = 0; k0 < MKEY; k0 += 64) {
    __syncthreads();
#pragma unroll
    for (int c = 0; c < 9; ++c)
      gll16(asrc + k0 * 2 + soff[c], adst + c * 1024);
    __syncthreads();
#pragma unroll
    for (int ks = 0; ks < 2; ++ks) {
      const int kofs = ks * 32 + q16 * 8;
      f16x8 ah[4], bh[4];
#pragma unroll
      for (int i = 0; i < 4; i++)
        ah[i] = *(const f16x8*)&Ah[(64 * wr + 16 * i + l16) * LDK + kofs];
#pragma unroll
      for (int j = 0; j < 4; j++)
        bh[j] = *(const f16x8*)&Bh[(64 * wc + 16 * j + l16) * LDK + kofs];
#pragma unroll
      for (int i = 0; i < 4; i++)
#pragma unroll
        for (int j = 0; j < 4; j++)
          acc[i][j] = __builtin_amdgcn_mfma_f32_16x16x32_f16(ah[i], bh[j], acc[i][j], 0, 0, 0);
    }
  }

  // Epilogue: per-query-row max of dot * (1/kn) over this block's 128 keys
  int ncol[4];
  float rk[4];
#pragma unroll
  for (int j = 0; j < 4; j++) {
    ncol[j] = ntile * BN + 64 * wc + 16 * j + l16;
    rk[j] = (ncol[j] < NMEM) ? rkn[ncol[j]] : 0.f;
  }
#pragma unroll
  for (int i = 0; i < 4; i++) {
#pragma unroll
    for (int r = 0; r < 4; r++) {
      float m = -FLT_MAX;
#pragma unroll
      for (int j = 0; j < 4; j++)
        if (ncol[j] < NMEM) m = fmaxf(m, acc[i][j][r] * rk[j]);
#pragma unroll
      for (int off = 1; off < 16; off <<= 1)
        m = fmaxf(m, __shfl_xor(m, off, 64));
      if (l16 == 0) cand[64 * wr + 16 * i + 4 * q16 + r][wc] = m;
    }
  }
  __syncthreads();
  if (t < BM) {
    float v = fmaxf(cand[t][0], cand[t][1]);
    bmax[(size_t)(mtile * BM + t) * NTILES + ntile] = v;
  }
}

// Pass 2: per query, find qualifying blocks, exact double rescore, gather values.
// Deterministic capture: fp16 screen error <= (2^-10 + 2^-16)*||q|| in score units;
// margin 2.5e-3*||q|| > 2x bound.
__global__ __launch_bounds__(256) void rescore_gather(
    const float* __restrict__ q, const float* __restrict__ mem,
    const float* __restrict__ bmax, float* __restrict__ out) {
  __shared__ __align__(16) float qs[256];
  __shared__ float red1[4], red2[4];
  __shared__ int list[96];
  __shared__ int nlist;
  __shared__ double wbest[4];
  __shared__ int wbidx[4];
  __shared__ int widx;

  const int qi = blockIdx.x;
  const int t = threadIdx.x, w = t >> 6, lane = t & 63;

  float qv = q[(size_t)qi * 256 + t];
  qs[t] = qv;
  float ss = qv * qv;
#pragma unroll
  for (int off = 32; off >= 1; off >>= 1) ss += __shfl_xor(ss, off, 64);
  if (lane == 0) red1[w] = ss;
  if (t == 0) nlist = 0;
  __syncthreads();
  const float qn = sqrtf(red1[0] + red1[1] + red1[2] + red1[3]);
  const float margin = 2.5e-3f * qn;

  const float* brow = bmax + (size_t)qi * NTILES;
  float gm = -FLT_MAX;
  for (int i = t; i < NTILES; i += 256) gm = fmaxf(gm, brow[i]);
#pragma unroll
  for (int off = 32; off >= 1; off >>= 1) gm = fmaxf(gm, __shfl_xor(gm, off, 64));
  if (lane == 0) red2[w] = gm;
  __syncthreads();
  gm = fmaxf(fmaxf(red2[0], red2[1]), fmaxf(red2[2], red2[3]));
  const float thresh = gm - margin;

  for (int i = t; i < NTILES; i += 256)
    if (brow[i] >= thresh) {
      int p = atomicAdd(&nlist, 1);
      if (p < 96) list[p] = i;
    }
  __syncthreads();
  const int nl = min(nlist, 96);

  double bestv = -1e300;
  int bestidx = 0x7fffffff;
  for (int c = 0; c < nl; ++c) {
    const int nt = list[c];
    for (int k = w; k < 128; k += 4) {  // one wave per key row
      const int row = nt * 128 + k;
      if (row >= NMEM) continue;
      const float4 kv = *(const float4*)&mem[(size_t)row * 512 + lane * 4];
      const float4 q4 = *(const float4*)&qs[lane * 4];
      double d = (double)kv.x * q4.x + (double)kv.y * q4.y +
                 (double)kv.z * q4.z + (double)kv.w * q4.w;
      double s2 = (double)kv.x * kv.x + (double)kv.y * kv.y +
                  (double)kv.z * kv.z + (double)kv.w * kv.w;
#pragma unroll
      for (int off = 32; off >= 1; off >>= 1) {
        d += __shfl_xor(d, off, 64);
        s2 += __shfl_xor(s2, off, 64);
      }
      const double score = d / sqrt(s2 > 1e-300 ? s2 : 1e-300);
      if (score > bestv || (score == bestv && row < bestidx)) {
        bestv = score;
        bestidx = row;
      }
    }
  }
  if (lane == 0) { wbest[w] = bestv; wbidx[w] = bestidx; }
  __syncthreads();
  if (t == 0) {
    double bv = wbest[0];
    int bi = wbidx[0];
#pragma unroll
    for (int w2 = 1; w2 < 4; ++w2)
      if (wbest[w2] > bv || (wbest[w2] == bv && wbidx[w2] < bi)) {
        bv = wbest[w2];
        bi = wbidx[w2];
      }
    widx = bi;
  }
  __syncthreads();
  out[(size_t)qi * 256 + t] = mem[(size_t)widx * 512 + 256 + t];
}

extern "C" void kernel_launch(void* const* d_in, const int* in_sizes, int n_in,
                              void* d_out, int out_size, void* d_ws, size_t ws_size,
                              hipStream_t stream) {
  const float* query = (const float*)d_in[0];
  const float* memory = (const float*)d_in[1];
  float* out = (float*)d_out;

  char* p = (char*)d_ws;
  unsigned short* qh = (unsigned short*)p; p += (size_t)NQ * MKEY * 2;
  unsigned short* kh = (unsigned short*)p; p += (size_t)NPAD * MKEY * 2;
  float* rkn = (float*)p; p += (size_t)NPAD * 4;
  float* bmax = (float*)p; p += (size_t)NQ * NTILES * 4;

  hipLaunchKernelGGL(conv_query, dim3(NQ * MKEY / 256), dim3(256), 0, stream, query, qh);
  hipLaunchKernelGGL(conv_keys, dim3(NPAD / 4), dim3(256), 0, stream, memory, kh, rkn);
  hipLaunchKernelGGL(gemm_screen, dim3(GRID), dim3(256), 0, stream, qh, kh, rkn, bmax);
  hipLaunchKernelGGL(rescore_gather, dim3(NQ), dim3(256), 0, stream,
                     query, memory, bmax, out);
}

// Round 5
// 469.155 us; speedup vs baseline: 1.5890x; 1.1322x over previous
//
#include <hip/hip_runtime.h>
#include <hip/hip_fp16.h>
#include <float.h>

#define MKEY 256        // K (key size)
#define NMEM 100000     // memory rows
#define NPAD 100096     // 782 * 128
#define NQ   2048       // queries
#define BM 128
#define BN 128
#define LDK 72          // padded LDS row stride in halfwords (144 B = 9 x 16B chunks)
#define NTILES 782      // NPAD / BN
#define MTILES 16       // NQ / BM
#define GRID (128 * 98) // XCD-clustered id space; ntile>=782 early-exits
#define KEYBLOCKS (NPAD / 4)   // 25024

typedef _Float16 f16x8 __attribute__((ext_vector_type(8)));
typedef float f32x4 __attribute__((ext_vector_type(4)));

__device__ inline void gll16(const void* g, void* l) {
  __builtin_amdgcn_global_load_lds(
      (const __attribute__((address_space(1))) unsigned*)g,
      (__attribute__((address_space(3))) unsigned*)l, 16, 0, 0);
}

// merged: keys fp32 -> fp16 + inv key norm (blocks 0..25023); query fp32 -> fp16
// (blocks 25024..27071)
__global__ void convert(const float* __restrict__ q, const float* __restrict__ mem,
                        unsigned short* __restrict__ qh, unsigned short* __restrict__ kh,
                        float* __restrict__ rkn) {
  const int b = blockIdx.x;
  if (b >= KEYBLOCKS) {
    const int i = (b - KEYBLOCKS) * 256 + threadIdx.x;
    qh[i] = __half_as_ushort(__float2half(q[i]));
    return;
  }
  const int t = threadIdx.x, lane = t & 63, w = t >> 6;
  const int row = b * 4 + w;
  if (row < NMEM) {
    const float4 v = *(const float4*)&mem[(long)row * 512 + lane * 4];
    float fs[4] = {v.x, v.y, v.z, v.w};
    unsigned short hb[4];
    float ss = 0.f;
#pragma unroll
    for (int c = 0; c < 4; ++c) {
      ss += fs[c] * fs[c];
      hb[c] = __half_as_ushort(__float2half(fs[c]));
    }
    *(ushort4*)&kh[(long)row * 256 + lane * 4] = make_ushort4(hb[0], hb[1], hb[2], hb[3]);
#pragma unroll
    for (int off = 32; off >= 1; off >>= 1) ss += __shfl_xor(ss, off, 64);
    if (lane == 0) rkn[row] = 1.0f / sqrtf(fmaxf(ss, 1e-30f));
  } else {
    *(ushort4*)&kh[(long)row * 256 + lane * 4] = make_ushort4(0, 0, 0, 0);
    if (lane == 0) rkn[row] = 0.f;
  }
}

// Pass 1: fp16 screening GEMM; writes per-(query, ntile) max score transposed:
// bmaxT[ntile * NQ + query]  (coalesced 512B store per block)
__global__ __launch_bounds__(256, 4) void gemm_screen(
    const unsigned short* __restrict__ qh, const unsigned short* __restrict__ kh,
    const float* __restrict__ rkn, float* __restrict__ bmaxT) {
  __shared__ unsigned short Ah[BM * LDK], Bh[BN * LDK];
  __shared__ float cand[BM][2];

  // XCD-clustered decode: same-ntile blocks land on the same XCD (ids = mod 8)
  const int id = blockIdx.x;
  const int mtile = (id >> 3) & 15;
  const int ntile = (id & 7) + 8 * (id >> 7);
  if (ntile >= NTILES) return;

  const int t = threadIdx.x;
  const int w = t >> 6;
  const int lane = t & 63;
  const int wr = w >> 1, wc = w & 1;
  const int q16 = lane >> 4, l16 = lane & 15;

  // staging: waves 0,1 -> Ah; waves 2,3 -> Bh; each wave 9 calls (576 slots)
  int soff[9];
#pragma unroll
  for (int c = 0; c < 9; ++c) {
    int s = (w & 1) * 576 + c * 64 + lane;  // slot 0..1151 within array
    int r = s / 9, ch = s - r * 9;
    if (ch == 8) ch = 0;                    // pad chunk -> dummy load (L1 hit)
    soff[c] = r * 512 + ch * 16;            // bytes in source (row stride 512B)
  }
  const char* asrc = (const char*)((w < 2) ? qh : kh) +
                     (size_t)(((w < 2) ? mtile : ntile) * 128) * 512;
  char* adst = (char*)((w < 2) ? Ah : Bh) + (w & 1) * 576 * 16;

  f32x4 acc[4][4];
#pragma unroll
  for (int i = 0; i < 4; i++)
#pragma unroll
    for (int j = 0; j < 4; j++) acc[i][j] = (f32x4){0.f, 0.f, 0.f, 0.f};

  for (int k0 = 0; k0 < MKEY; k0 += 64) {
    __syncthreads();
#pragma unroll
    for (int c = 0; c < 9; ++c)
      gll16(asrc + k0 * 2 + soff[c], adst + c * 1024);
    __syncthreads();
#pragma unroll
    for (int ks = 0; ks < 2; ++ks) {
      const int kofs = ks * 32 + q16 * 8;
      f16x8 ah[4], bh[4];
#pragma unroll
      for (int i = 0; i < 4; i++)
        ah[i] = *(const f16x8*)&Ah[(64 * wr + 16 * i + l16) * LDK + kofs];
#pragma unroll
      for (int j = 0; j < 4; j++)
        bh[j] = *(const f16x8*)&Bh[(64 * wc + 16 * j + l16) * LDK + kofs];
#pragma unroll
      for (int i = 0; i < 4; i++)
#pragma unroll
        for (int j = 0; j < 4; j++)
          acc[i][j] = __builtin_amdgcn_mfma_f32_16x16x32_f16(ah[i], bh[j], acc[i][j], 0, 0, 0);
    }
  }

  // Epilogue: per-query-row max of dot * (1/kn) over this block's 128 keys
  int ncol[4];
  float rk[4];
#pragma unroll
  for (int j = 0; j < 4; j++) {
    ncol[j] = ntile * BN + 64 * wc + 16 * j + l16;
    rk[j] = (ncol[j] < NMEM) ? rkn[ncol[j]] : 0.f;
  }
#pragma unroll
  for (int i = 0; i < 4; i++) {
#pragma unroll
    for (int r = 0; r < 4; r++) {
      float m = -FLT_MAX;
#pragma unroll
      for (int j = 0; j < 4; j++)
        if (ncol[j] < NMEM) m = fmaxf(m, acc[i][j][r] * rk[j]);
#pragma unroll
      for (int off = 1; off < 16; off <<= 1)
        m = fmaxf(m, __shfl_xor(m, off, 64));
      if (l16 == 0) cand[64 * wr + 16 * i + 4 * q16 + r][wc] = m;
    }
  }
  __syncthreads();
  if (t < BM) {
    float v = fmaxf(cand[t][0], cand[t][1]);
    bmaxT[(size_t)ntile * NQ + mtile * BM + t] = v;  // coalesced
  }
}

// Pass 2: per query, find qualifying blocks, exact double rescore, gather values.
// fp16 screen error <= ~1e-3*||q|| in score units; margin 2.5e-3*||q|| > 2x bound.
__global__ __launch_bounds__(256) void rescore_gather(
    const float* __restrict__ q, const float* __restrict__ mem,
    const float* __restrict__ bmaxT, float* __restrict__ out) {
  __shared__ float red2[4];
  __shared__ int list[64];
  __shared__ int nlist;
  __shared__ double wb[4];
  __shared__ int wbi[4];
  __shared__ int widx;

  const int qi = blockIdx.x;
  const int t = threadIdx.x, w = t >> 6, lane = t & 63;
  const int r4 = lane >> 4, d16 = lane & 15;

  // this lane's 16 query dims, in registers once
  float4 q4[4];
#pragma unroll
  for (int c = 0; c < 4; ++c)
    q4[c] = *(const float4*)&q[(size_t)qi * 256 + d16 * 16 + c * 4];

  // ||q||: each dim covered by 4 lanes (r4 groups) -> wave sum = 4*||q||^2
  float ss = 0.f;
#pragma unroll
  for (int c = 0; c < 4; ++c)
    ss += q4[c].x * q4[c].x + q4[c].y * q4[c].y + q4[c].z * q4[c].z + q4[c].w * q4[c].w;
#pragma unroll
  for (int off = 32; off >= 1; off >>= 1) ss += __shfl_xor(ss, off, 64);
  const float qn = sqrtf(ss * 0.25f);
  const float margin = 2.5e-3f * qn;

  if (t == 0) nlist = 0;

  // global screened max over block maxima
  float gm = -FLT_MAX;
  for (int i = t; i < NTILES; i += 256) gm = fmaxf(gm, bmaxT[(size_t)i * NQ + qi]);
#pragma unroll
  for (int off = 32; off >= 1; off >>= 1) gm = fmaxf(gm, __shfl_xor(gm, off, 64));
  if (lane == 0) red2[w] = gm;
  __syncthreads();
  gm = fmaxf(fmaxf(red2[0], red2[1]), fmaxf(red2[2], red2[3]));
  const float thresh = gm - margin;

  for (int i = t; i < NTILES; i += 256)
    if (bmaxT[(size_t)i * NQ + qi] >= thresh) {
      int p = atomicAdd(&nlist, 1);
      if (p < 64) list[p] = i;
    }
  __syncthreads();
  const int nl = min(nlist, 64);

  double bestv = -1e300;
  int bestidx = 0x7fffffff;
  for (int c = 0; c < nl; ++c) {
    const int nt = list[c];
#pragma unroll 2
    for (int pass = 0; pass < 8; ++pass) {
      const int row = nt * 128 + w * 32 + pass * 4 + r4;
      double d = 0.0, s2 = 0.0;
      if (row < NMEM) {
#pragma unroll
        for (int c4 = 0; c4 < 4; ++c4) {
          const float4 kv = *(const float4*)&mem[(size_t)row * 512 + d16 * 16 + c4 * 4];
          d += (double)kv.x * q4[c4].x + (double)kv.y * q4[c4].y +
               (double)kv.z * q4[c4].z + (double)kv.w * q4[c4].w;
          s2 += (double)kv.x * kv.x + (double)kv.y * kv.y +
                (double)kv.z * kv.z + (double)kv.w * kv.w;
        }
      }
#pragma unroll
      for (int off = 1; off < 16; off <<= 1) {
        d += __shfl_xor(d, off, 64);
        s2 += __shfl_xor(s2, off, 64);
      }
      if (d16 == 0 && row < NMEM) {
        const double score = d / sqrt(s2 > 1e-300 ? s2 : 1e-300);
        if (score > bestv || (score == bestv && row < bestidx)) {
          bestv = score;
          bestidx = row;
        }
      }
    }
  }
  // cross-lane argmax (lanes with d16!=0 hold -1e300)
#pragma unroll
  for (int off = 1; off < 64; off <<= 1) {
    const double ov = __shfl_xor(bestv, off, 64);
    const int oi = __shfl_xor(bestidx, off, 64);
    if (ov > bestv || (ov == bestv && oi < bestidx)) {
      bestv = ov;
      bestidx = oi;
    }
  }
  if (lane == 0) { wb[w] = bestv; wbi[w] = bestidx; }
  __syncthreads();
  if (t == 0) {
    double bv = wb[0];
    int bi = wbi[0];
#pragma unroll
    for (int w2 = 1; w2 < 4; ++w2)
      if (wb[w2] > bv || (wb[w2] == bv && wbi[w2] < bi)) {
        bv = wb[w2];
        bi = wbi[w2];
      }
    widx = bi;
  }
  __syncthreads();
  out[(size_t)qi * 256 + t] = mem[(size_t)widx * 512 + 256 + t];
}

extern "C" void kernel_launch(void* const* d_in, const int* in_sizes, int n_in,
                              void* d_out, int out_size, void* d_ws, size_t ws_size,
                              hipStream_t stream) {
  const float* query = (const float*)d_in[0];
  const float* memory = (const float*)d_in[1];
  float* out = (float*)d_out;

  char* p = (char*)d_ws;
  unsigned short* qh = (unsigned short*)p; p += (size_t)NQ * MKEY * 2;
  unsigned short* kh = (unsigned short*)p; p += (size_t)NPAD * MKEY * 2;
  float* rkn = (float*)p; p += (size_t)NPAD * 4;
  float* bmaxT = (float*)p; p += (size_t)NQ * NTILES * 4;

  hipLaunchKernelGGL(convert, dim3(KEYBLOCKS + NQ * MKEY / 256 / 1), dim3(256), 0, stream,
                     query, memory, qh, kh, rkn);
  hipLaunchKernelGGL(gemm_screen, dim3(GRID), dim3(256), 0, stream, qh, kh, rkn, bmaxT);
  hipLaunchKernelGGL(rescore_gather, dim3(NQ), dim3(256), 0, stream,
                     query, memory, bmaxT, out);
}